// Round 1
// baseline (40839.627 us; speedup 1.0000x reference)
//
#include <hip/hip_runtime.h>

#define B_ 64
#define S_ 256
#define F_ 256
#define H_ 1024

__device__ __forceinline__ float sig(float v) { return 1.0f / (1.0f + __expf(-v)); }
// tanh(v) = 1 - 2/(exp(2v)+1); handles +/-inf safely
__device__ __forceinline__ float tanh_(float v) { return 1.0f - 2.0f / (__expf(2.0f * v) + 1.0f); }

#define DOT4(acc, w, v) acc += (w).x*(v).x + (w).y*(v).y + (w).z*(v).z + (w).w*(v).w

// ---------------- layer 0: gates = [x_t, action] @ Wih^T + h0 @ Whh^T + b; pointwise ----------------
// grid 512 blocks x 256 thr. Block owns 2 h-units (8 gate rows). Thread: b = t&63,
// u = (t>>6)&1, half = t>>7. half0: x(256) + action(256) + h0[0:256]; half1: h0[256:1024].
__global__ __launch_bounds__(256, 2)
void lstm0_step(const float* __restrict__ x,
                const float* __restrict__ Wih, const float* __restrict__ Whh,
                const float* __restrict__ bih, const float* __restrict__ bhh,
                const float* __restrict__ action,
                const float* __restrict__ h_in,
                float* __restrict__ h_out,
                float* __restrict__ c,
                int tstep)
{
    __shared__ float red[8 * 64];  // [u*4+g][b]
    const int t = threadIdx.x;
    const int b = t & 63;
    const int slot = t >> 6;
    const int u = slot & 1;
    const int half = slot >> 1;
    const int unit = blockIdx.x * 2 + u;
    const int ru = __builtin_amdgcn_readfirstlane(unit);  // wave-uniform -> scalar loads for weights

    const float4* __restrict__ wi0 = (const float4*)(Wih + (size_t)(0 * H_ + ru) * 512);
    const float4* __restrict__ wi1 = (const float4*)(Wih + (size_t)(1 * H_ + ru) * 512);
    const float4* __restrict__ wi2 = (const float4*)(Wih + (size_t)(2 * H_ + ru) * 512);
    const float4* __restrict__ wi3 = (const float4*)(Wih + (size_t)(3 * H_ + ru) * 512);
    const float4* __restrict__ wh0 = (const float4*)(Whh + (size_t)(0 * H_ + ru) * 1024);
    const float4* __restrict__ wh1 = (const float4*)(Whh + (size_t)(1 * H_ + ru) * 1024);
    const float4* __restrict__ wh2 = (const float4*)(Whh + (size_t)(2 * H_ + ru) * 1024);
    const float4* __restrict__ wh3 = (const float4*)(Whh + (size_t)(3 * H_ + ru) * 1024);
    const float4* __restrict__ hv = (const float4*)(h_in + (size_t)b * H_);

    float a0, a1, a2, a3;
    if (half == 0) {
        a0 = bih[0 * H_ + ru] + bhh[0 * H_ + ru];
        a1 = bih[1 * H_ + ru] + bhh[1 * H_ + ru];
        a2 = bih[2 * H_ + ru] + bhh[2 * H_ + ru];
        a3 = bih[3 * H_ + ru] + bhh[3 * H_ + ru];
        const float4* __restrict__ xv = (const float4*)(x + ((size_t)b * S_ + tstep) * F_);
        const float4* __restrict__ av = (const float4*)(action + (size_t)b * F_);
        #pragma unroll 4
        for (int k = 0; k < 64; ++k) {
            float4 v = xv[k];
            float4 w;
            w = wi0[k]; DOT4(a0, w, v);
            w = wi1[k]; DOT4(a1, w, v);
            w = wi2[k]; DOT4(a2, w, v);
            w = wi3[k]; DOT4(a3, w, v);
        }
        #pragma unroll 4
        for (int k = 0; k < 64; ++k) {
            float4 v = av[k];
            float4 w;
            w = wi0[64 + k]; DOT4(a0, w, v);
            w = wi1[64 + k]; DOT4(a1, w, v);
            w = wi2[64 + k]; DOT4(a2, w, v);
            w = wi3[64 + k]; DOT4(a3, w, v);
        }
        #pragma unroll 4
        for (int k = 0; k < 64; ++k) {
            float4 v = hv[k];
            float4 w;
            w = wh0[k]; DOT4(a0, w, v);
            w = wh1[k]; DOT4(a1, w, v);
            w = wh2[k]; DOT4(a2, w, v);
            w = wh3[k]; DOT4(a3, w, v);
        }
    } else {
        a0 = a1 = a2 = a3 = 0.0f;
        #pragma unroll 4
        for (int k = 64; k < 256; ++k) {
            float4 v = hv[k];
            float4 w;
            w = wh0[k]; DOT4(a0, w, v);
            w = wh1[k]; DOT4(a1, w, v);
            w = wh2[k]; DOT4(a2, w, v);
            w = wh3[k]; DOT4(a3, w, v);
        }
        red[(u * 4 + 0) * 64 + b] = a0;
        red[(u * 4 + 1) * 64 + b] = a1;
        red[(u * 4 + 2) * 64 + b] = a2;
        red[(u * 4 + 3) * 64 + b] = a3;
    }
    __syncthreads();
    if (half == 0) {
        a0 += red[(u * 4 + 0) * 64 + b];
        a1 += red[(u * 4 + 1) * 64 + b];
        a2 += red[(u * 4 + 2) * 64 + b];
        a3 += red[(u * 4 + 3) * 64 + b];
        float gi = sig(a0), gf = sig(a1), gg = tanh_(a2), go = sig(a3);
        size_t idx = (size_t)b * H_ + unit;
        float cn = gf * c[idx] + gi * gg;
        c[idx] = cn;
        h_out[idx] = go * tanh_(cn);
    }
}

// ---------------- layer 1: gates = h0n @ Wih1^T + h1 @ Whh1^T + b; pointwise ----------------
// grid 512 x 256. half0: ih part (K=1024); half1: hh part (K=1024).
__global__ __launch_bounds__(256, 2)
void lstm1_step(const float* __restrict__ h0n,
                const float* __restrict__ Wih, const float* __restrict__ Whh,
                const float* __restrict__ bih, const float* __restrict__ bhh,
                const float* __restrict__ h_in,
                float* __restrict__ h_out,
                float* __restrict__ c)
{
    __shared__ float red[8 * 64];
    const int t = threadIdx.x;
    const int b = t & 63;
    const int slot = t >> 6;
    const int u = slot & 1;
    const int half = slot >> 1;
    const int unit = blockIdx.x * 2 + u;
    const int ru = __builtin_amdgcn_readfirstlane(unit);

    float a0, a1, a2, a3;
    if (half == 0) {
        const float4* __restrict__ w0 = (const float4*)(Wih + (size_t)(0 * H_ + ru) * 1024);
        const float4* __restrict__ w1 = (const float4*)(Wih + (size_t)(1 * H_ + ru) * 1024);
        const float4* __restrict__ w2 = (const float4*)(Wih + (size_t)(2 * H_ + ru) * 1024);
        const float4* __restrict__ w3 = (const float4*)(Wih + (size_t)(3 * H_ + ru) * 1024);
        const float4* __restrict__ vv = (const float4*)(h0n + (size_t)b * H_);
        a0 = bih[0 * H_ + ru] + bhh[0 * H_ + ru];
        a1 = bih[1 * H_ + ru] + bhh[1 * H_ + ru];
        a2 = bih[2 * H_ + ru] + bhh[2 * H_ + ru];
        a3 = bih[3 * H_ + ru] + bhh[3 * H_ + ru];
        #pragma unroll 4
        for (int k = 0; k < 256; ++k) {
            float4 v = vv[k];
            float4 w;
            w = w0[k]; DOT4(a0, w, v);
            w = w1[k]; DOT4(a1, w, v);
            w = w2[k]; DOT4(a2, w, v);
            w = w3[k]; DOT4(a3, w, v);
        }
    } else {
        const float4* __restrict__ w0 = (const float4*)(Whh + (size_t)(0 * H_ + ru) * 1024);
        const float4* __restrict__ w1 = (const float4*)(Whh + (size_t)(1 * H_ + ru) * 1024);
        const float4* __restrict__ w2 = (const float4*)(Whh + (size_t)(2 * H_ + ru) * 1024);
        const float4* __restrict__ w3 = (const float4*)(Whh + (size_t)(3 * H_ + ru) * 1024);
        const float4* __restrict__ vv = (const float4*)(h_in + (size_t)b * H_);
        a0 = a1 = a2 = a3 = 0.0f;
        #pragma unroll 4
        for (int k = 0; k < 256; ++k) {
            float4 v = vv[k];
            float4 w;
            w = w0[k]; DOT4(a0, w, v);
            w = w1[k]; DOT4(a1, w, v);
            w = w2[k]; DOT4(a2, w, v);
            w = w3[k]; DOT4(a3, w, v);
        }
        red[(u * 4 + 0) * 64 + b] = a0;
        red[(u * 4 + 1) * 64 + b] = a1;
        red[(u * 4 + 2) * 64 + b] = a2;
        red[(u * 4 + 3) * 64 + b] = a3;
    }
    __syncthreads();
    if (half == 0) {
        a0 += red[(u * 4 + 0) * 64 + b];
        a1 += red[(u * 4 + 1) * 64 + b];
        a2 += red[(u * 4 + 2) * 64 + b];
        a3 += red[(u * 4 + 3) * 64 + b];
        float gi = sig(a0), gf = sig(a1), gg = tanh_(a2), go = sig(a3);
        size_t idx = (size_t)b * H_ + unit;
        float cn = gf * c[idx] + gi * gg;
        c[idx] = cn;
        h_out[idx] = go * tanh_(cn);
    }
}

// ---------------- fc + blend + output ----------------
// grid 128 x 256. Block owns 2 output channels; K=1024 split across halves.
__global__ __launch_bounds__(256, 2)
void fc_blend(const float* __restrict__ h1n, const float* __restrict__ fcW,
              const float* __restrict__ fcb, const float* __restrict__ x,
              float* __restrict__ action, float* __restrict__ out, int tstep)
{
    __shared__ float red[2 * 64];
    const int t = threadIdx.x;
    const int b = t & 63;
    const int slot = t >> 6;
    const int u = slot & 1;
    const int half = slot >> 1;
    const int cu = blockIdx.x * 2 + u;
    const int rc = __builtin_amdgcn_readfirstlane(cu);

    const float4* __restrict__ wv = (const float4*)(fcW + (size_t)rc * H_);
    const float4* __restrict__ hv = (const float4*)(h1n + (size_t)b * H_);
    float a = (half == 0) ? fcb[rc] : 0.0f;
    const int k0 = half * 128;
    #pragma unroll 4
    for (int k = 0; k < 128; ++k) {
        float4 v = hv[k0 + k];
        float4 w = wv[k0 + k];
        DOT4(a, w, v);
    }
    if (half == 1) red[u * 64 + b] = a;
    __syncthreads();
    if (half == 0) {
        a += red[u * 64 + b];
        size_t xi = ((size_t)b * S_ + tstep) * F_ + cu;
        float xv = x[xi];
        float na;
        if (tstep == 0) {
            na = xv;
        } else {
            float ap = action[(size_t)b * F_ + cu];
            // ((1+0.5*0.3)x + 0.5*0.3*a + 0.5*0.4*out) / (1+0.5*(0.3+0.3+0.4))
            na = (1.15f * xv + 0.15f * ap + 0.2f * a) * (1.0f / 1.5f);
        }
        action[(size_t)b * F_ + cu] = na;
        out[xi] = na;
    }
}

__global__ void zero_ws(float* __restrict__ p, int n)
{
    int i = blockIdx.x * blockDim.x + threadIdx.x;
    if (i < n) p[i] = 0.0f;
}

extern "C" void kernel_launch(void* const* d_in, const int* in_sizes, int n_in,
                              void* d_out, int out_size, void* d_ws, size_t ws_size,
                              hipStream_t stream)
{
    const float* x    = (const float*)d_in[0];
    const float* Wih0 = (const float*)d_in[1];
    const float* Whh0 = (const float*)d_in[2];
    const float* bih0 = (const float*)d_in[3];
    const float* bhh0 = (const float*)d_in[4];
    const float* Wih1 = (const float*)d_in[5];
    const float* Whh1 = (const float*)d_in[6];
    const float* bih1 = (const float*)d_in[7];
    const float* bhh1 = (const float*)d_in[8];
    const float* fcW  = (const float*)d_in[9];
    const float* fcb  = (const float*)d_in[10];
    float* outp = (float*)d_out;

    float* ws = (float*)d_ws;
    const int BH = B_ * H_;            // 65536
    float* h0  = ws;                   // [2][B][H] ping-pong
    float* c0  = ws + 2 * BH;          // [B][H]
    float* h1  = ws + 3 * BH;          // [2][B][H]
    float* c1  = ws + 5 * BH;          // [B][H]
    float* act = ws + 6 * BH;          // [B][F]
    const int n_state = 6 * BH + B_ * F_;  // 409600 floats

    zero_ws<<<(n_state + 255) / 256, 256, 0, stream>>>(ws, n_state);

    for (int tstep = 0; tstep < S_; ++tstep) {
        const int cur = tstep & 1, nxt = cur ^ 1;
        lstm0_step<<<512, 256, 0, stream>>>(x, Wih0, Whh0, bih0, bhh0, act,
                                            h0 + cur * BH, h0 + nxt * BH, c0, tstep);
        lstm1_step<<<512, 256, 0, stream>>>(h0 + nxt * BH, Wih1, Whh1, bih1, bhh1,
                                            h1 + cur * BH, h1 + nxt * BH, c1);
        fc_blend<<<128, 256, 0, stream>>>(h1 + nxt * BH, fcW, fcb, x, act, outp, tstep);
    }
}

// Round 2
// 9778.719 us; speedup vs baseline: 4.1764x; 4.1764x over previous
//
#include <hip/hip_runtime.h>

#define B_ 64
#define S_ 256
#define F_ 256
#define H_ 1024

typedef __attribute__((ext_vector_type(8))) short bf16x8;
typedef __attribute__((ext_vector_type(4))) float f32x4;

#define MFMA(a, b, c) __builtin_amdgcn_mfma_f32_16x16x32_bf16(a, b, c, 0, 0, 0)

__device__ __forceinline__ float sig(float v) { return 1.0f / (1.0f + __expf(-v)); }
__device__ __forceinline__ float tanh_(float v) { return 1.0f - 2.0f / (__expf(2.0f * v) + 1.0f); }
__device__ __forceinline__ short bfr(float f) {  // fp32 -> bf16 RNE
    unsigned u = __float_as_uint(f);
    u += 0x7fffu + ((u >> 16) & 1u);
    return (short)(u >> 16);
}

// ============ one-time (per call) weight conversion, fragment-major ============
// dest layout: [nf][kf][64 lanes][8], element (lane,j): gate-row' = nf*16+(lane&15),
// k = kf*32+(lane>>4)*8+j.  Gate rows permuted: row' = u*4+g  (u=unit, g=gate).
__global__ __launch_bounds__(256) void conv_w0(const float* __restrict__ Wih,
                                               const float* __restrict__ Whh,
                                               short* __restrict__ dst) {
    int tid = blockIdx.x * 256 + threadIdx.x;   // [nf 256][kf 48][lane 64]
    int lane = tid & 63;
    int kf = (tid >> 6) % 48;
    int nf = tid / (48 * 64);
    int rowp = nf * 16 + (lane & 15);
    int u = rowp >> 2, g = rowp & 3;
    int k = kf * 32 + (lane >> 4) * 8;
    const float* src = (k < 512) ? (Wih + (g * H_ + u) * 512 + k)
                                 : (Whh + (size_t)(g * H_ + u) * 1024 + (k - 512));
    bf16x8 o;
    #pragma unroll
    for (int j = 0; j < 8; ++j) o[j] = bfr(src[j]);
    *(bf16x8*)(dst + (size_t)tid * 8) = o;
}

__global__ __launch_bounds__(256) void conv_w1(const float* __restrict__ Wih,
                                               const float* __restrict__ Whh,
                                               short* __restrict__ dst) {
    int tid = blockIdx.x * 256 + threadIdx.x;   // [nf 256][kf 64][lane 64]
    int lane = tid & 63;
    int kf = (tid >> 6) % 64;
    int nf = tid / (64 * 64);
    int rowp = nf * 16 + (lane & 15);
    int u = rowp >> 2, g = rowp & 3;
    int k = kf * 32 + (lane >> 4) * 8;
    const float* src = (k < 1024) ? (Wih + (size_t)(g * H_ + u) * 1024 + k)
                                  : (Whh + (size_t)(g * H_ + u) * 1024 + (k - 1024));
    bf16x8 o;
    #pragma unroll
    for (int j = 0; j < 8; ++j) o[j] = bfr(src[j]);
    *(bf16x8*)(dst + (size_t)tid * 8) = o;
}

__global__ __launch_bounds__(256) void conv_wf(const float* __restrict__ W,
                                               short* __restrict__ dst) {
    int tid = blockIdx.x * 256 + threadIdx.x;   // [nf 16][kf 32][lane 64]
    int lane = tid & 63;
    int kf = (tid >> 6) % 32;
    int nf = tid / (32 * 64);
    int row = nf * 16 + (lane & 15);            // no gate permute for fc
    int k = kf * 32 + (lane >> 4) * 8;
    const float* src = W + (size_t)row * 1024 + k;
    bf16x8 o;
    #pragma unroll
    for (int j = 0; j < 8; ++j) o[j] = bfr(src[j]);
    *(bf16x8*)(dst + (size_t)tid * 8) = o;
}

__global__ void conv_bias(const float* bi0, const float* bh0,
                          const float* bi1, const float* bh1,
                          float* bs0, float* bs1) {
    int tid = blockIdx.x * 256 + threadIdx.x;
    if (tid < 4096) {
        int u = tid >> 2, g = tid & 3;
        bs0[tid] = bi0[g * H_ + u] + bh0[g * H_ + u];
    } else if (tid < 8192) {
        int t2 = tid - 4096;
        int u = t2 >> 2, g = t2 & 3;
        bs1[t2] = bi1[g * H_ + u] + bh1[g * H_ + u];
    }
}

__global__ void zero_f(float* __restrict__ p, int n) {
    int i = blockIdx.x * blockDim.x + threadIdx.x;
    if (i < n) p[i] = 0.0f;
}

// ============ phase A: layer0 gates + pointwise ============
// grid 256 x 256. block = 4 units (16 permuted gate rows = 1 N-frag). waves split K (48 kf / 4).
__global__ __launch_bounds__(256) void phaseA(const float* __restrict__ x,
        const short* __restrict__ W0b, const float* __restrict__ bs0,
        const short* __restrict__ actSt, const short* __restrict__ h0Ac,
        short* __restrict__ h0An, short* __restrict__ L1Ac,
        float* __restrict__ c0, int t) {
    __shared__ f32x4 red[1024];
    const int tid = threadIdx.x, lane = tid & 63, w = tid >> 6;
    const int nf = blockIdx.x;
    f32x4 acc0 = {0,0,0,0}, acc1 = {0,0,0,0}, acc2 = {0,0,0,0}, acc3 = {0,0,0,0};
    for (int kk = 0; kk < 12; ++kk) {
        int kf = w * 12 + kk;
        bf16x8 bfg = *(const bf16x8*)(W0b + ((size_t)(nf * 48 + kf) * 64 + lane) * 8);
        bf16x8 a0, a1, a2, a3;
        if (kf < 8) {                       // x_t, convert inline
            int kb = kf * 32 + (lane >> 4) * 8;
            #define LDX(mm, dst) { \
                const float* xp = x + ((size_t)((mm) * 16 + (lane & 15)) * S_ + t) * F_ + kb; \
                float4 v0 = *(const float4*)xp; float4 v1 = *(const float4*)(xp + 4); \
                dst[0]=bfr(v0.x); dst[1]=bfr(v0.y); dst[2]=bfr(v0.z); dst[3]=bfr(v0.w); \
                dst[4]=bfr(v1.x); dst[5]=bfr(v1.y); dst[6]=bfr(v1.z); dst[7]=bfr(v1.w); }
            LDX(0, a0) LDX(1, a1) LDX(2, a2) LDX(3, a3)
            #undef LDX
        } else if (kf < 16) {               // action (staged bf16)
            int base = (kf - 8) * 4;
            a0 = *(const bf16x8*)(actSt + ((size_t)(base + 0) * 64 + lane) * 8);
            a1 = *(const bf16x8*)(actSt + ((size_t)(base + 1) * 64 + lane) * 8);
            a2 = *(const bf16x8*)(actSt + ((size_t)(base + 2) * 64 + lane) * 8);
            a3 = *(const bf16x8*)(actSt + ((size_t)(base + 3) * 64 + lane) * 8);
        } else {                            // h0 prev (staged bf16)
            int base = (kf - 16) * 4;
            a0 = *(const bf16x8*)(h0Ac + ((size_t)(base + 0) * 64 + lane) * 8);
            a1 = *(const bf16x8*)(h0Ac + ((size_t)(base + 1) * 64 + lane) * 8);
            a2 = *(const bf16x8*)(h0Ac + ((size_t)(base + 2) * 64 + lane) * 8);
            a3 = *(const bf16x8*)(h0Ac + ((size_t)(base + 3) * 64 + lane) * 8);
        }
        acc0 = MFMA(a0, bfg, acc0);
        acc1 = MFMA(a1, bfg, acc1);
        acc2 = MFMA(a2, bfg, acc2);
        acc3 = MFMA(a3, bfg, acc3);
    }
    red[(w * 4 + 0) * 64 + lane] = acc0;
    red[(w * 4 + 1) * 64 + lane] = acc1;
    red[(w * 4 + 2) * 64 + lane] = acc2;
    red[(w * 4 + 3) * 64 + lane] = acc3;
    __syncthreads();
    f32x4 s = red[(0 * 4 + w) * 64 + lane];
    s += red[(1 * 4 + w) * 64 + lane];
    s += red[(2 * 4 + w) * 64 + lane];
    s += red[(3 * 4 + w) * 64 + lane];
    const float bias = bs0[nf * 16 + (lane & 15)];
    const int g1 = lane & 1, g2 = lane & 2;
    const int u = nf * 4 + ((lane & 15) >> 2);
    #pragma unroll
    for (int r = 0; r < 4; ++r) {
        float v = s[r] + bias;
        float x1 = __shfl_xor(v, 1), x2 = __shfl_xor(v, 2), x3 = __shfl_xor(v, 3);
        float aL = g1 ? x1 : v,  aH = g1 ? x3 : x2;
        float bL = g1 ? v  : x1, bH = g1 ? x2 : x3;
        float i_ = g2 ? aH : aL;
        float f_ = g2 ? bH : bL;
        float gc = g2 ? aL : aH;
        float o_ = g2 ? bL : bH;
        i_ = sig(i_); f_ = sig(f_); o_ = sig(o_); gc = tanh_(gc);
        int b = w * 16 + (lane >> 4) * 4 + r;
        float cn = f_ * c0[b * H_ + u] + i_ * gc;
        float hn = o_ * tanh_(cn);
        if ((lane & 3) == 0) {
            c0[b * H_ + u] = cn;
            short hb = bfr(hn);
            int ls = ((u & 31) >> 3) * 16 + (b & 15);
            size_t e = (size_t)((u >> 5) * 4 + w) * 512 + ls * 8 + (u & 7);
            L1Ac[e] = hb;   // layer1 A-operand, k_local = u
            h0An[e] = hb;   // next-step layer0 A-operand, k_local = 512+u (same intra-buffer index)
        }
    }
}

// ============ phase B: layer1 gates + pointwise ============
__global__ __launch_bounds__(256) void phaseB(
        const short* __restrict__ W1b, const float* __restrict__ bs1,
        const short* __restrict__ L1Ac, short* __restrict__ L1An,
        short* __restrict__ fcA, float* __restrict__ c1) {
    __shared__ f32x4 red[1024];
    const int tid = threadIdx.x, lane = tid & 63, w = tid >> 6;
    const int nf = blockIdx.x;
    f32x4 acc0 = {0,0,0,0}, acc1 = {0,0,0,0}, acc2 = {0,0,0,0}, acc3 = {0,0,0,0};
    for (int kk = 0; kk < 16; ++kk) {
        int kf = w * 16 + kk;
        bf16x8 bfg = *(const bf16x8*)(W1b + ((size_t)(nf * 64 + kf) * 64 + lane) * 8);
        int base = kf * 4;
        bf16x8 a0 = *(const bf16x8*)(L1Ac + ((size_t)(base + 0) * 64 + lane) * 8);
        bf16x8 a1 = *(const bf16x8*)(L1Ac + ((size_t)(base + 1) * 64 + lane) * 8);
        bf16x8 a2 = *(const bf16x8*)(L1Ac + ((size_t)(base + 2) * 64 + lane) * 8);
        bf16x8 a3 = *(const bf16x8*)(L1Ac + ((size_t)(base + 3) * 64 + lane) * 8);
        acc0 = MFMA(a0, bfg, acc0);
        acc1 = MFMA(a1, bfg, acc1);
        acc2 = MFMA(a2, bfg, acc2);
        acc3 = MFMA(a3, bfg, acc3);
    }
    red[(w * 4 + 0) * 64 + lane] = acc0;
    red[(w * 4 + 1) * 64 + lane] = acc1;
    red[(w * 4 + 2) * 64 + lane] = acc2;
    red[(w * 4 + 3) * 64 + lane] = acc3;
    __syncthreads();
    f32x4 s = red[(0 * 4 + w) * 64 + lane];
    s += red[(1 * 4 + w) * 64 + lane];
    s += red[(2 * 4 + w) * 64 + lane];
    s += red[(3 * 4 + w) * 64 + lane];
    const float bias = bs1[nf * 16 + (lane & 15)];
    const int g1 = lane & 1, g2 = lane & 2;
    const int u = nf * 4 + ((lane & 15) >> 2);
    #pragma unroll
    for (int r = 0; r < 4; ++r) {
        float v = s[r] + bias;
        float x1 = __shfl_xor(v, 1), x2 = __shfl_xor(v, 2), x3 = __shfl_xor(v, 3);
        float aL = g1 ? x1 : v,  aH = g1 ? x3 : x2;
        float bL = g1 ? v  : x1, bH = g1 ? x2 : x3;
        float i_ = g2 ? aH : aL;
        float f_ = g2 ? bH : bL;
        float gc = g2 ? aL : aH;
        float o_ = g2 ? bL : bH;
        i_ = sig(i_); f_ = sig(f_); o_ = sig(o_); gc = tanh_(gc);
        int b = w * 16 + (lane >> 4) * 4 + r;
        float cn = f_ * c1[b * H_ + u] + i_ * gc;
        float hn = o_ * tanh_(cn);
        if ((lane & 3) == 0) {
            c1[b * H_ + u] = cn;
            short hb = bfr(hn);
            int ls = ((u & 31) >> 3) * 16 + (b & 15);
            fcA[(size_t)((u >> 5) * 4 + w) * 512 + ls * 8 + (u & 7)] = hb;          // fc A, k=u
            L1An[(size_t)((32 + (u >> 5)) * 4 + w) * 512 + ls * 8 + (u & 7)] = hb;  // next-step h1, k=1024+u
        }
    }
}

// ============ phase C: fc + blend + output + action staging ============
__global__ __launch_bounds__(256) void phaseC(const float* __restrict__ x,
        const short* __restrict__ Wfb, const float* __restrict__ fcb,
        const short* __restrict__ fcA, float* __restrict__ act,
        float* __restrict__ out, short* __restrict__ actStW, int t) {
    __shared__ f32x4 red[1024];
    const int tid = threadIdx.x, lane = tid & 63, w = tid >> 6;
    const int nf = blockIdx.x;  // 0..15
    f32x4 acc0 = {0,0,0,0}, acc1 = {0,0,0,0}, acc2 = {0,0,0,0}, acc3 = {0,0,0,0};
    for (int kk = 0; kk < 8; ++kk) {
        int kf = w * 8 + kk;
        bf16x8 bfg = *(const bf16x8*)(Wfb + ((size_t)(nf * 32 + kf) * 64 + lane) * 8);
        int base = kf * 4;
        bf16x8 a0 = *(const bf16x8*)(fcA + ((size_t)(base + 0) * 64 + lane) * 8);
        bf16x8 a1 = *(const bf16x8*)(fcA + ((size_t)(base + 1) * 64 + lane) * 8);
        bf16x8 a2 = *(const bf16x8*)(fcA + ((size_t)(base + 2) * 64 + lane) * 8);
        bf16x8 a3 = *(const bf16x8*)(fcA + ((size_t)(base + 3) * 64 + lane) * 8);
        acc0 = MFMA(a0, bfg, acc0);
        acc1 = MFMA(a1, bfg, acc1);
        acc2 = MFMA(a2, bfg, acc2);
        acc3 = MFMA(a3, bfg, acc3);
    }
    red[(w * 4 + 0) * 64 + lane] = acc0;
    red[(w * 4 + 1) * 64 + lane] = acc1;
    red[(w * 4 + 2) * 64 + lane] = acc2;
    red[(w * 4 + 3) * 64 + lane] = acc3;
    __syncthreads();
    f32x4 s = red[(0 * 4 + w) * 64 + lane];
    s += red[(1 * 4 + w) * 64 + lane];
    s += red[(2 * 4 + w) * 64 + lane];
    s += red[(3 * 4 + w) * 64 + lane];
    const int c = nf * 16 + (lane & 15);
    const float ov_b = fcb[c];
    #pragma unroll
    for (int r = 0; r < 4; ++r) {
        float ov = s[r] + ov_b;
        int b = w * 16 + (lane >> 4) * 4 + r;
        size_t xi = ((size_t)b * S_ + t) * F_ + c;
        float xv = x[xi];
        float na;
        if (t == 0) na = xv;
        else na = (1.15f * xv + 0.15f * act[b * F_ + c] + 0.2f * ov) * (1.0f / 1.5f);
        act[b * F_ + c] = na;
        out[xi] = na;
        int ls = ((c & 31) >> 3) * 16 + (b & 15);
        actStW[(size_t)((c >> 5) * 4 + w) * 512 + ls * 8 + (c & 7)] = bfr(na);  // layer0 A, k=256+c
    }
}

extern "C" void kernel_launch(void* const* d_in, const int* in_sizes, int n_in,
                              void* d_out, int out_size, void* d_ws, size_t ws_size,
                              hipStream_t stream) {
    const float* x    = (const float*)d_in[0];
    const float* Wih0 = (const float*)d_in[1];
    const float* Whh0 = (const float*)d_in[2];
    const float* bih0 = (const float*)d_in[3];
    const float* bhh0 = (const float*)d_in[4];
    const float* Wih1 = (const float*)d_in[5];
    const float* Whh1 = (const float*)d_in[6];
    const float* bih1 = (const float*)d_in[7];
    const float* bhh1 = (const float*)d_in[8];
    const float* fcW  = (const float*)d_in[9];
    const float* fcb  = (const float*)d_in[10];
    float* outp = (float*)d_out;

    char* ws = (char*)d_ws;
    short* W0b  = (short*)(ws + 0);          // 12,582,912 B
    short* W1b  = (short*)(ws + 12582912);   // 16,777,216 B
    short* Wfb  = (short*)(ws + 29360128);   //    524,288 B
    float* bs0  = (float*)(ws + 29884416);   //     16,384 B
    float* bs1  = (float*)(ws + 29900800);   //     16,384 B
    short* h0A  = (short*)(ws + 29917184);   // 2 x 131,072 B (65536 elems each)
    short* actSt= (short*)(ws + 30179328);   //     32,768 B
    short* L1A  = (short*)(ws + 30212096);   // 2 x 262,144 B (131072 elems each)
    short* fcA  = (short*)(ws + 30736384);   //    131,072 B
    float* c0   = (float*)(ws + 30867456);   //    262,144 B
    float* c1   = (float*)(ws + 31129600);   //    262,144 B
    float* act  = (float*)(ws + 31391744);   //     65,536 B   (total ~31.5 MB)

    conv_w0<<<3072, 256, 0, stream>>>(Wih0, Whh0, W0b);
    conv_w1<<<4096, 256, 0, stream>>>(Wih1, Whh1, W1b);
    conv_wf<<<128, 256, 0, stream>>>(fcW, Wfb);
    conv_bias<<<32, 256, 0, stream>>>(bih0, bhh0, bih1, bhh1, bs0, bs1);
    zero_f<<<1504, 256, 0, stream>>>((float*)(ws + 29917184), 385024);  // all state buffers

    for (int t = 0; t < S_; ++t) {
        const int cur = t & 1, nxt = cur ^ 1;
        phaseA<<<256, 256, 0, stream>>>(x, W0b, bs0, actSt,
                                        h0A + (size_t)cur * 65536, h0A + (size_t)nxt * 65536,
                                        L1A + (size_t)cur * 131072, c0, t);
        phaseB<<<256, 256, 0, stream>>>(W1b, bs1,
                                        L1A + (size_t)cur * 131072, L1A + (size_t)nxt * 131072,
                                        fcA, c1);
        phaseC<<<16, 256, 0, stream>>>(x, Wfb, fcb, fcA, act, outp, actSt, t);
    }
}